// Round 1
// baseline (6432.916 us; speedup 1.0000x reference)
//
#include <hip/hip_runtime.h>
#include <hip/hip_bf16.h>

#define HD 2
#define LAYERS 4
#define RELS 16
#define BASES 8

// --- K0: W[l][r][i][o] = sum_b comp[l,r,b] * V[l,b,i,o]; also zero the dot accumulator.
__global__ void prep_kernel(const float* __restrict__ V, const float* __restrict__ comp,
                            float* __restrict__ W, float* __restrict__ acc) {
    int idx = threadIdx.x;            // 0..255 = l*64 + r*4 + io
    if (idx < LAYERS * RELS * 4) {
        int l  = idx >> 6;
        int r  = (idx >> 2) & (RELS - 1);
        int io = idx & 3;
        float s = 0.f;
        for (int b = 0; b < BASES; ++b)
            s += comp[(l * RELS + r) * BASES + b] * V[(l * BASES + b) * 4 + io];
        W[idx] = s;
    }
    if (idx == 0) *acc = 0.f;
}

// --- zero a float buffer (vectorized)
__global__ void zero_kernel(float4* __restrict__ p, int n4) {
    int i = blockIdx.x * blockDim.x + threadIdx.x;
    int stride = gridDim.x * blockDim.x;
    for (; i < n4; i += stride) p[i] = make_float4(0.f, 0.f, 0.f, 0.f);
}

// --- edge pass: h[dst] += (x[src] @ W[type]) * norm
__global__ __launch_bounds__(256) void edge_kernel(
    const float* __restrict__ x,          // [N*2] node features (read via float2)
    const int*  __restrict__ src,
    const int*  __restrict__ dst,
    const int*  __restrict__ typ,
    const float* __restrict__ norm,
    const float* __restrict__ Wl,         // [64] = [16][2][2] this layer
    float* __restrict__ h,                // [N*2] accumulator (pre-zeroed)
    int E)
{
    __shared__ float sW[64];
    if (threadIdx.x < 64) sW[threadIdx.x] = Wl[threadIdx.x];
    __syncthreads();

    const float2* __restrict__ x2 = (const float2*)x;
    const int4*  __restrict__ src4  = (const int4*)src;
    const int4*  __restrict__ dst4  = (const int4*)dst;
    const int4*  __restrict__ typ4  = (const int4*)typ;
    const float4* __restrict__ nrm4 = (const float4*)norm;

    int tid    = blockIdx.x * blockDim.x + threadIdx.x;
    int stride = gridDim.x * blockDim.x;
    int E4 = E >> 2;

    for (int g = tid; g < E4; g += stride) {
        int4 s = src4[g];
        int4 d = dst4[g];
        int4 t = typ4[g];
        float4 nm = nrm4[g];

#define EDGE(SS, DD, TT, NN)                                        \
        {                                                           \
            float2 xv = x2[SS];                                     \
            int wb = (TT) << 2;                                     \
            float m0 = (xv.x * sW[wb + 0] + xv.y * sW[wb + 2]) * (NN); \
            float m1 = (xv.x * sW[wb + 1] + xv.y * sW[wb + 3]) * (NN); \
            atomicAdd(&h[2 * (size_t)(DD)],     m0);                \
            atomicAdd(&h[2 * (size_t)(DD) + 1], m1);                \
        }
        EDGE(s.x, d.x, t.x, nm.x)
        EDGE(s.y, d.y, t.y, nm.y)
        EDGE(s.z, d.z, t.z, nm.z)
        EDGE(s.w, d.w, t.w, nm.w)
    }
    // tail (E not divisible by 4)
    for (int e = (E4 << 2) + tid; e < E; e += stride) {
        int s = src[e], d = dst[e], t = typ[e];
        float nm = norm[e];
        float2 xv = x2[s];
        int wb = t << 2;
        float m0 = (xv.x * sW[wb + 0] + xv.y * sW[wb + 2]) * nm;
        float m1 = (xv.x * sW[wb + 1] + xv.y * sW[wb + 3]) * nm;
        atomicAdd(&h[2 * (size_t)d],     m0);
        atomicAdd(&h[2 * (size_t)d + 1], m1);
    }
#undef EDGE
}

// --- node pass: x = maybe_skip( maybe_relu( h + bias ) ); in-place safe
__global__ void node_kernel(const float* __restrict__ h,
                            const float* __restrict__ bias_l,   // [2]
                            const float* __restrict__ skip,     // nullable
                            float* __restrict__ xout,
                            int N, int do_relu)
{
    float b0 = bias_l[0], b1 = bias_l[1];
    const float2* __restrict__ h2 = (const float2*)h;
    const float2* __restrict__ s2 = (const float2*)skip;
    float2* __restrict__ o2 = (float2*)xout;
    int i = blockIdx.x * blockDim.x + threadIdx.x;
    int stride = gridDim.x * blockDim.x;
    for (; i < N; i += stride) {
        float2 v = h2[i];
        v.x += b0; v.y += b1;
        if (do_relu) { v.x = fmaxf(v.x, 0.f); v.y = fmaxf(v.y, 0.f); }
        if (skip) { float2 sv = s2[i]; v.x += sv.x; v.y += sv.y; }
        o2[i] = v;
    }
}

// --- final dot: acc += sum(a*b)
__global__ __launch_bounds__(256) void dot_kernel(const float* __restrict__ a,
                                                  const float* __restrict__ b,
                                                  float* __restrict__ acc, int n)
{
    int i = blockIdx.x * blockDim.x + threadIdx.x;
    int stride = gridDim.x * blockDim.x;
    float s = 0.f;
    int n4 = n >> 2;
    const float4* __restrict__ a4 = (const float4*)a;
    const float4* __restrict__ b4 = (const float4*)b;
    for (int g = i; g < n4; g += stride) {
        float4 av = a4[g], bv = b4[g];
        s += av.x * bv.x + av.y * bv.y + av.z * bv.z + av.w * bv.w;
    }
    for (int e = (n4 << 2) + i; e < n; e += stride) s += a[e] * b[e];

    for (int off = 32; off > 0; off >>= 1) s += __shfl_down(s, off, 64);
    __shared__ float wsum[4];
    int lane = threadIdx.x & 63, wv = threadIdx.x >> 6;
    if (lane == 0) wsum[wv] = s;
    __syncthreads();
    if (threadIdx.x == 0) {
        atomicAdd(acc, wsum[0] + wsum[1] + wsum[2] + wsum[3]);
    }
}

__global__ void finalize_kernel(const float* __restrict__ acc,
                                const float* __restrict__ b_mlp,
                                float* __restrict__ out) {
    float v = *acc + b_mlp[0];
    out[0] = 1.f / (1.f + expf(-v));
}

extern "C" void kernel_launch(void* const* d_in, const int* in_sizes, int n_in,
                              void* d_out, int out_size, void* d_ws, size_t ws_size,
                              hipStream_t stream) {
    const float* features = (const float*)d_in[0];   // [N*2]
    const float* norm     = (const float*)d_in[1];   // [E]
    const float* V        = (const float*)d_in[2];   // [L,B,2,2]
    const float* comp     = (const float*)d_in[3];   // [L,R,B]
    const float* bias     = (const float*)d_in[4];   // [L,2]
    const float* w_mlp    = (const float*)d_in[5];   // [N*2]
    const float* b_mlp    = (const float*)d_in[6];   // [1]
    const int*   esrc     = (const int*)d_in[7];     // [E]
    const int*   edst     = (const int*)d_in[8];
    const int*   etyp     = (const int*)d_in[9];

    int NH = in_sizes[0];        // 2N
    int N  = NH / 2;
    int E  = in_sizes[7];

    float* A   = (float*)d_ws;           // node buffer 0  [NH]
    float* B   = A + NH;                 // node buffer 1  [NH]
    float* C   = B + NH;                 // node buffer 2  [NH]
    float* W   = C + NH;                 // [L*R*4] = 256
    float* acc = W + 256;                // [1]

    int zb = (NH / 4 + 255) / 256;       // zero-kernel blocks
    int eb = ((E + 3) / 4 + 255) / 256;  // edge-kernel blocks
    int nb = (N + 255) / 256;            // node-kernel blocks
    int db = (NH / 4 + 255) / 256;       // dot-kernel blocks

    prep_kernel<<<1, 256, 0, stream>>>(V, comp, W, acc);

    // layer 0: h->A, x1 = relu(A + b0)            (skip stays = features)
    zero_kernel<<<zb, 256, 0, stream>>>((float4*)A, NH / 4);
    edge_kernel<<<eb, 256, 0, stream>>>(features, esrc, edst, etyp, norm, W + 0, A, E);
    node_kernel<<<nb, 256, 0, stream>>>(A, bias + 0, nullptr, A, N, 1);

    // layer 1: h->B, x2 = relu(B + b1) + features (skip becomes B)
    zero_kernel<<<zb, 256, 0, stream>>>((float4*)B, NH / 4);
    edge_kernel<<<eb, 256, 0, stream>>>(A, esrc, edst, etyp, norm, W + 64, B, E);
    node_kernel<<<nb, 256, 0, stream>>>(B, bias + 2, features, B, N, 1);

    // layer 2: h->C, x3 = relu(C + b2)
    zero_kernel<<<zb, 256, 0, stream>>>((float4*)C, NH / 4);
    edge_kernel<<<eb, 256, 0, stream>>>(B, esrc, edst, etyp, norm, W + 128, C, E);
    node_kernel<<<nb, 256, 0, stream>>>(C, bias + 4, nullptr, C, N, 1);

    // layer 3: h->A, x4 = (A + b3) + B (no relu, last layer)
    zero_kernel<<<zb, 256, 0, stream>>>((float4*)A, NH / 4);
    edge_kernel<<<eb, 256, 0, stream>>>(C, esrc, edst, etyp, norm, W + 192, A, E);
    node_kernel<<<nb, 256, 0, stream>>>(A, bias + 6, B, A, N, 0);

    // MLP head: sigmoid(dot(x4, w_mlp) + b_mlp)
    dot_kernel<<<db, 256, 0, stream>>>(A, w_mlp, acc, NH);
    finalize_kernel<<<1, 1, 0, stream>>>(acc, b_mlp, (float*)d_out);
}

// Round 2
// 1431.091 us; speedup vs baseline: 4.4951x; 4.4951x over previous
//
#include <hip/hip_runtime.h>
#include <hip/hip_bf16.h>

#define HD 2
#define LAYERS 4
#define RELS 16
#define BASES 8

#define NB   4096      // dst buckets (bucket = dst >> 8), covers N < 2^20
#define BSH  8         // 256 nodes per bucket
#define SBLK 1024      // sort chunk blocks
#define TPB  256

// ============================ common ============================

// W[l][r][i][o] = sum_b comp[l,r,b] * V[l,b,i,o]; zero dot accumulator.
__global__ void prep_kernel(const float* __restrict__ V, const float* __restrict__ comp,
                            float* __restrict__ W, float* __restrict__ acc) {
    int idx = threadIdx.x;            // 0..255 = l*64 + r*4 + io
    if (idx < LAYERS * RELS * 4) {
        int l  = idx >> 6;
        int r  = (idx >> 2) & (RELS - 1);
        int io = idx & 3;
        float s = 0.f;
        for (int b = 0; b < BASES; ++b)
            s += comp[(l * RELS + r) * BASES + b] * V[(l * BASES + b) * 4 + io];
        W[idx] = s;
    }
    if (idx == 0) *acc = 0.f;
}

__global__ void finalize_kernel(const float* __restrict__ acc,
                                const float* __restrict__ b_mlp,
                                float* __restrict__ out) {
    float v = *acc + b_mlp[0];
    out[0] = 1.f / (1.f + expf(-v));
}

// ============================ sort path ============================

// S1: per-chunk histogram of dst buckets.  blockhist[blk*NB + bucket]
__global__ __launch_bounds__(TPB) void hist_kernel(const int* __restrict__ dst,
                                                   unsigned* __restrict__ blockhist,
                                                   int E, int per) {
    __shared__ unsigned hist[NB];
    for (int i = threadIdx.x; i < NB; i += TPB) hist[i] = 0u;
    __syncthreads();
    int blk = blockIdx.x;
    int e0 = blk * per;
    int e1 = min(e0 + per, E);
    for (int e = e0 + threadIdx.x; e < e1; e += TPB)
        atomicAdd(&hist[((unsigned)dst[e]) >> BSH], 1u);
    __syncthreads();
    for (int i = threadIdx.x; i < NB; i += TPB)
        blockhist[(size_t)blk * NB + i] = hist[i];
}

// S2a: per-bucket column exclusive scan over chunks (in place); totals[bucket] out.
__global__ __launch_bounds__(TPB) void colscan_kernel(unsigned* __restrict__ blockhist,
                                                      unsigned* __restrict__ totals) {
    int bucket = blockIdx.x;
    int t = threadIdx.x;
    unsigned v[4], pre[4];
    unsigned run = 0;
    for (int j = 0; j < 4; ++j) {
        int blk = 4 * t + j;
        v[j] = blockhist[(size_t)blk * NB + bucket];
        pre[j] = run;
        run += v[j];
    }
    __shared__ unsigned s[TPB];
    s[t] = run;
    __syncthreads();
    for (int off = 1; off < TPB; off <<= 1) {
        unsigned x = (t >= off) ? s[t - off] : 0u;
        __syncthreads();
        s[t] += x;
        __syncthreads();
    }
    unsigned base = s[t] - run;   // exclusive prefix of this thread's 4-chunk group
    for (int j = 0; j < 4; ++j) {
        int blk = 4 * t + j;
        blockhist[(size_t)blk * NB + bucket] = base + pre[j];
    }
    if (t == TPB - 1) totals[bucket] = s[TPB - 1];
}

// S2b: exclusive scan of 4096 totals -> base[NB+1]
__global__ __launch_bounds__(TPB) void scan_kernel(const unsigned* __restrict__ totals,
                                                   unsigned* __restrict__ base) {
    int t = threadIdx.x;
    unsigned v[16], pre[16];
    unsigned run = 0;
    for (int j = 0; j < 16; ++j) {
        v[j] = totals[16 * t + j];
        pre[j] = run;
        run += v[j];
    }
    __shared__ unsigned s[TPB];
    s[t] = run;
    __syncthreads();
    for (int off = 1; off < TPB; off <<= 1) {
        unsigned x = (t >= off) ? s[t - off] : 0u;
        __syncthreads();
        s[t] += x;
        __syncthreads();
    }
    unsigned b0 = s[t] - run;
    for (int j = 0; j < 16; ++j)
        base[16 * t + j] = b0 + pre[j];
    if (t == TPB - 1) base[NB] = s[TPB - 1];
}

// S3: scatter edges into dst-bucket order, packing src|typ|dst_off + norm (8B/edge).
__global__ __launch_bounds__(TPB) void scatter_kernel(const int* __restrict__ src,
                                                      const int* __restrict__ dst,
                                                      const int* __restrict__ typ,
                                                      const float* __restrict__ norm,
                                                      const unsigned* __restrict__ blockhist,
                                                      const unsigned* __restrict__ base,
                                                      uint2* __restrict__ packed,
                                                      int E, int per) {
    __shared__ unsigned cnt[NB];
    int blk = blockIdx.x;
    for (int i = threadIdx.x; i < NB; i += TPB)
        cnt[i] = blockhist[(size_t)blk * NB + i] + base[i];
    __syncthreads();
    int e0 = blk * per;
    int e1 = min(e0 + per, E);
    for (int e = e0 + threadIdx.x; e < e1; e += TPB) {
        unsigned d = (unsigned)dst[e];
        unsigned s = (unsigned)src[e];
        unsigned t = (unsigned)typ[e];
        float nm = norm[e];
        unsigned bucket = d >> BSH;
        unsigned pos = atomicAdd(&cnt[bucket], 1u);   // LDS atomic, block scope
        packed[pos] = make_uint2(s | (t << 20) | ((d & 255u) << 24),
                                 __float_as_uint(nm));
    }
}

// Edge pass: one workgroup per dst bucket. LDS accumulation, fused epilogue
// (bias, relu, skip-add, optional store, optional w_mlp dot partial).
__global__ __launch_bounds__(TPB) void bucket_edge_kernel(
    const uint2* __restrict__ packed,
    const unsigned* __restrict__ base,
    const float2* __restrict__ x2,        // gather source [N]
    const float* __restrict__ Wl,         // [64] this layer
    const float* __restrict__ bias2,      // [2]
    const float2* __restrict__ skip2,     // nullable
    float2* __restrict__ out2,            // nullable
    const float2* __restrict__ w2,        // nullable (w_mlp as float2[N])
    float* __restrict__ acc,              // dot accumulator
    int N, int do_relu)
{
    __shared__ float acc0[256];
    __shared__ float acc1[256];
    __shared__ float sW[64];
    __shared__ float wred[4];

    int t = threadIdx.x;
    acc0[t] = 0.f;
    acc1[t] = 0.f;
    if (t < 64) sW[t] = Wl[t];
    __syncthreads();

    int b  = blockIdx.x;
    int e0 = (int)base[b];
    int e1 = (int)base[b + 1];
    for (int e = e0 + t; e < e1; e += TPB) {
        uint2 p = packed[e];
        unsigned w0   = p.x;
        unsigned src  = w0 & 0xFFFFFu;
        unsigned typ  = (w0 >> 20) & 0xFu;
        unsigned doff = w0 >> 24;
        float nm = __uint_as_float(p.y);
        float2 xv = x2[src];
        int wb = (int)(typ << 2);
        float m0 = (xv.x * sW[wb + 0] + xv.y * sW[wb + 2]) * nm;
        float m1 = (xv.x * sW[wb + 1] + xv.y * sW[wb + 3]) * nm;
        atomicAdd(&acc0[doff], m0);
        atomicAdd(&acc1[doff], m1);
    }
    __syncthreads();

    int node = (b << BSH) + t;
    float part = 0.f;
    if (node < N) {
        float v0 = acc0[t] + bias2[0];
        float v1 = acc1[t] + bias2[1];
        if (do_relu) { v0 = fmaxf(v0, 0.f); v1 = fmaxf(v1, 0.f); }
        if (skip2) { float2 sv = skip2[node]; v0 += sv.x; v1 += sv.y; }
        if (out2)  out2[node] = make_float2(v0, v1);
        if (w2)    { float2 wv = w2[node]; part = v0 * wv.x + v1 * wv.y; }
    }
    if (w2) {
        for (int off = 32; off > 0; off >>= 1) part += __shfl_down(part, off, 64);
        int lane = t & 63, wv = t >> 6;
        if (lane == 0) wred[wv] = part;
        __syncthreads();
        if (t == 0) atomicAdd(acc, wred[0] + wred[1] + wred[2] + wred[3]);
    }
}

// ============================ fallback path (round-1, known-good) ============================

__global__ void zero_kernel(float4* __restrict__ p, int n4) {
    int i = blockIdx.x * blockDim.x + threadIdx.x;
    int stride = gridDim.x * blockDim.x;
    for (; i < n4; i += stride) p[i] = make_float4(0.f, 0.f, 0.f, 0.f);
}

__global__ __launch_bounds__(256) void edge_kernel(
    const float* __restrict__ x, const int* __restrict__ src,
    const int* __restrict__ dst, const int* __restrict__ typ,
    const float* __restrict__ norm, const float* __restrict__ Wl,
    float* __restrict__ h, int E)
{
    __shared__ float sW[64];
    if (threadIdx.x < 64) sW[threadIdx.x] = Wl[threadIdx.x];
    __syncthreads();
    const float2* __restrict__ x2 = (const float2*)x;
    int tid = blockIdx.x * blockDim.x + threadIdx.x;
    int stride = gridDim.x * blockDim.x;
    for (int e = tid; e < E; e += stride) {
        int s = src[e], d = dst[e], t = typ[e];
        float nm = norm[e];
        float2 xv = x2[s];
        int wb = t << 2;
        float m0 = (xv.x * sW[wb + 0] + xv.y * sW[wb + 2]) * nm;
        float m1 = (xv.x * sW[wb + 1] + xv.y * sW[wb + 3]) * nm;
        atomicAdd(&h[2 * (size_t)d],     m0);
        atomicAdd(&h[2 * (size_t)d + 1], m1);
    }
}

__global__ void node_kernel(const float* __restrict__ h, const float* __restrict__ bias_l,
                            const float* __restrict__ skip, float* __restrict__ xout,
                            int N, int do_relu)
{
    float b0 = bias_l[0], b1 = bias_l[1];
    const float2* __restrict__ h2 = (const float2*)h;
    const float2* __restrict__ s2 = (const float2*)skip;
    float2* __restrict__ o2 = (float2*)xout;
    int i = blockIdx.x * blockDim.x + threadIdx.x;
    int stride = gridDim.x * blockDim.x;
    for (; i < N; i += stride) {
        float2 v = h2[i];
        v.x += b0; v.y += b1;
        if (do_relu) { v.x = fmaxf(v.x, 0.f); v.y = fmaxf(v.y, 0.f); }
        if (skip) { float2 sv = s2[i]; v.x += sv.x; v.y += sv.y; }
        o2[i] = v;
    }
}

__global__ __launch_bounds__(256) void dot_kernel(const float* __restrict__ a,
                                                  const float* __restrict__ b,
                                                  float* __restrict__ acc, int n)
{
    int i = blockIdx.x * blockDim.x + threadIdx.x;
    int stride = gridDim.x * blockDim.x;
    float s = 0.f;
    int n4 = n >> 2;
    const float4* __restrict__ a4 = (const float4*)a;
    const float4* __restrict__ b4 = (const float4*)b;
    for (int g = i; g < n4; g += stride) {
        float4 av = a4[g], bv = b4[g];
        s += av.x * bv.x + av.y * bv.y + av.z * bv.z + av.w * bv.w;
    }
    for (int e = (n4 << 2) + i; e < n; e += stride) s += a[e] * b[e];
    for (int off = 32; off > 0; off >>= 1) s += __shfl_down(s, off, 64);
    __shared__ float wsum[4];
    int lane = threadIdx.x & 63, wv = threadIdx.x >> 6;
    if (lane == 0) wsum[wv] = s;
    __syncthreads();
    if (threadIdx.x == 0) atomicAdd(acc, wsum[0] + wsum[1] + wsum[2] + wsum[3]);
}

// ============================ launch ============================

static inline size_t align256(size_t x) { return (x + 255) & ~(size_t)255; }

extern "C" void kernel_launch(void* const* d_in, const int* in_sizes, int n_in,
                              void* d_out, int out_size, void* d_ws, size_t ws_size,
                              hipStream_t stream) {
    const float* features = (const float*)d_in[0];   // [N*2]
    const float* norm     = (const float*)d_in[1];   // [E]
    const float* V        = (const float*)d_in[2];   // [L,B,2,2]
    const float* comp     = (const float*)d_in[3];   // [L,R,B]
    const float* bias     = (const float*)d_in[4];   // [L,2]
    const float* w_mlp    = (const float*)d_in[5];   // [N*2]
    const float* b_mlp    = (const float*)d_in[6];   // [1]
    const int*   esrc     = (const int*)d_in[7];
    const int*   edst     = (const int*)d_in[8];
    const int*   etyp     = (const int*)d_in[9];

    int NH = in_sizes[0];
    int N  = NH / 2;
    int E  = in_sizes[7];

    char* ws = (char*)d_ws;
    size_t oA    = 0;
    size_t oB    = align256(oA + (size_t)NH * 4);
    size_t oC    = align256(oB + (size_t)NH * 4);
    size_t oW    = align256(oC + (size_t)NH * 4);
    size_t oAcc  = align256(oW + 1024);
    size_t oBase = align256(oAcc + 4);
    size_t oTot  = align256(oBase + (size_t)(NB + 1) * 4);
    size_t oHist = align256(oTot + (size_t)NB * 4);
    size_t oPack = align256(oHist + (size_t)SBLK * NB * 4);
    size_t REQ   = oPack + (size_t)E * 8;

    float* A   = (float*)(ws + oA);
    float* B   = (float*)(ws + oB);
    float* C   = (float*)(ws + oC);
    float* W   = (float*)(ws + oW);
    float* acc = (float*)(ws + oAcc);

    prep_kernel<<<1, 256, 0, stream>>>(V, comp, W, acc);

    if (ws_size >= REQ) {
        unsigned* base      = (unsigned*)(ws + oBase);
        unsigned* totals    = (unsigned*)(ws + oTot);
        unsigned* blockhist = (unsigned*)(ws + oHist);
        uint2*    packed    = (uint2*)(ws + oPack);

        int per = (E + SBLK - 1) / SBLK;

        hist_kernel   <<<SBLK, TPB, 0, stream>>>(edst, blockhist, E, per);
        colscan_kernel<<<NB,   TPB, 0, stream>>>(blockhist, totals);
        scan_kernel   <<<1,    TPB, 0, stream>>>(totals, base);
        scatter_kernel<<<SBLK, TPB, 0, stream>>>(esrc, edst, etyp, norm,
                                                 blockhist, base, packed, E, per);

        int nbkt = (N + 255) >> BSH;
        const float2* feat2 = (const float2*)features;
        const float2* w2    = (const float2*)w_mlp;

        // L0: A = relu(h0 + b0)
        bucket_edge_kernel<<<nbkt, TPB, 0, stream>>>(packed, base, feat2, W + 0,
            bias + 0, nullptr, (float2*)A, nullptr, acc, N, 1);
        // L1: B = relu(h1 + b1) + features
        bucket_edge_kernel<<<nbkt, TPB, 0, stream>>>(packed, base, (const float2*)A, W + 64,
            bias + 2, feat2, (float2*)B, nullptr, acc, N, 1);
        // L2: C = relu(h2 + b2)
        bucket_edge_kernel<<<nbkt, TPB, 0, stream>>>(packed, base, (const float2*)B, W + 128,
            bias + 4, nullptr, (float2*)C, nullptr, acc, N, 1);
        // L3: x4 = (h3 + b3) + B, fused dot with w_mlp (x4 not stored)
        bucket_edge_kernel<<<nbkt, TPB, 0, stream>>>(packed, base, (const float2*)C, W + 192,
            bias + 6, (const float2*)B, nullptr, w2, acc, N, 0);
    } else {
        // fallback: round-1 atomic path
        int zb = (NH / 4 + 255) / 256;
        int eb = (E / 4 + 255) / 256;
        int nb = (N + 255) / 256;
        int db = (NH / 4 + 255) / 256;

        zero_kernel<<<zb, 256, 0, stream>>>((float4*)A, NH / 4);
        edge_kernel<<<eb, 256, 0, stream>>>(features, esrc, edst, etyp, norm, W + 0, A, E);
        node_kernel<<<nb, 256, 0, stream>>>(A, bias + 0, nullptr, A, N, 1);

        zero_kernel<<<zb, 256, 0, stream>>>((float4*)B, NH / 4);
        edge_kernel<<<eb, 256, 0, stream>>>(A, esrc, edst, etyp, norm, W + 64, B, E);
        node_kernel<<<nb, 256, 0, stream>>>(B, bias + 2, features, B, N, 1);

        zero_kernel<<<zb, 256, 0, stream>>>((float4*)C, NH / 4);
        edge_kernel<<<eb, 256, 0, stream>>>(B, esrc, edst, etyp, norm, W + 128, C, E);
        node_kernel<<<nb, 256, 0, stream>>>(C, bias + 4, nullptr, C, N, 1);

        zero_kernel<<<zb, 256, 0, stream>>>((float4*)A, NH / 4);
        edge_kernel<<<eb, 256, 0, stream>>>(C, esrc, edst, etyp, norm, W + 192, A, E);
        node_kernel<<<nb, 256, 0, stream>>>(A, bias + 6, B, A, N, 0);

        dot_kernel<<<db, 256, 0, stream>>>(A, w_mlp, acc, NH);
    }

    finalize_kernel<<<1, 1, 0, stream>>>(acc, b_mlp, (float*)d_out);
}

// Round 4
// 1137.216 us; speedup vs baseline: 5.6567x; 1.2584x over previous
//
#include <hip/hip_runtime.h>
#include <hip/hip_bf16.h>
#include <hip/hip_fp16.h>

#define HD 2
#define LAYERS 4
#define RELS 16
#define BASES 8

#define NB   512       // dst buckets (bucket = dst >> BSH)
#define BSH  11        // 2048 nodes per bucket
#define SBLK 512       // sort chunk blocks
#define TPB  256

// ============================ common ============================

// W[l][r][i][o] = sum_b comp[l,r,b] * V[l,b,i,o]; zero dot accumulator.
__global__ void prep_kernel(const float* __restrict__ V, const float* __restrict__ comp,
                            float* __restrict__ W, float* __restrict__ acc) {
    int idx = threadIdx.x;            // 0..255 = l*64 + r*4 + io
    if (idx < LAYERS * RELS * 4) {
        int l  = idx >> 6;
        int r  = (idx >> 2) & (RELS - 1);
        int io = idx & 3;
        float s = 0.f;
        for (int b = 0; b < BASES; ++b)
            s += comp[(l * RELS + r) * BASES + b] * V[(l * BASES + b) * 4 + io];
        W[idx] = s;
    }
    if (idx == 0) *acc = 0.f;
}

__global__ void finalize_kernel(const float* __restrict__ acc,
                                const float* __restrict__ b_mlp,
                                float* __restrict__ out) {
    float v = *acc + b_mlp[0];
    out[0] = 1.f / (1.f + expf(-v));
}

// ============================ sort path ============================

// S1: per-chunk histogram of dst buckets.  blockhist[blk*NB + bucket]
__global__ __launch_bounds__(TPB) void hist_kernel(const int* __restrict__ dst,
                                                   unsigned* __restrict__ blockhist,
                                                   int E, int per) {
    __shared__ unsigned hist[NB];
    for (int i = threadIdx.x; i < NB; i += TPB) hist[i] = 0u;
    __syncthreads();
    int blk = blockIdx.x;
    int e0 = blk * per;              // multiple of 4
    int e1 = min(e0 + per, E);
    const int4* dst4 = (const int4*)dst;
    int g0 = e0 >> 2, g1 = e1 >> 2;
    for (int g = g0 + threadIdx.x; g < g1; g += TPB) {
        int4 d = dst4[g];
        atomicAdd(&hist[((unsigned)d.x) >> BSH], 1u);
        atomicAdd(&hist[((unsigned)d.y) >> BSH], 1u);
        atomicAdd(&hist[((unsigned)d.z) >> BSH], 1u);
        atomicAdd(&hist[((unsigned)d.w) >> BSH], 1u);
    }
    for (int e = (g1 << 2) + threadIdx.x; e < e1; e += TPB)   // tail (E%4)
        atomicAdd(&hist[((unsigned)dst[e]) >> BSH], 1u);
    __syncthreads();
    for (int i = threadIdx.x; i < NB; i += TPB)
        blockhist[(size_t)blk * NB + i] = hist[i];
}

// S2a: per-bucket column exclusive scan over chunks (in place); totals[bucket] out.
// SBLK/TPB = 2 chunks per thread.
__global__ __launch_bounds__(TPB) void colscan_kernel(unsigned* __restrict__ blockhist,
                                                      unsigned* __restrict__ totals) {
    int bucket = blockIdx.x;
    int t = threadIdx.x;
    unsigned v0 = blockhist[(size_t)(2 * t)     * NB + bucket];
    unsigned v1 = blockhist[(size_t)(2 * t + 1) * NB + bucket];
    unsigned run = v0 + v1;
    __shared__ unsigned s[TPB];
    s[t] = run;
    __syncthreads();
    for (int off = 1; off < TPB; off <<= 1) {
        unsigned x = (t >= off) ? s[t - off] : 0u;
        __syncthreads();
        s[t] += x;
        __syncthreads();
    }
    unsigned base = s[t] - run;
    blockhist[(size_t)(2 * t)     * NB + bucket] = base;
    blockhist[(size_t)(2 * t + 1) * NB + bucket] = base + v0;
    if (t == TPB - 1) totals[bucket] = s[TPB - 1];
}

// S2b: exclusive scan of NB totals -> base[NB+1].  NB/TPB = 2 per thread.
__global__ __launch_bounds__(TPB) void scan_kernel(const unsigned* __restrict__ totals,
                                                   unsigned* __restrict__ base) {
    int t = threadIdx.x;
    unsigned v0 = totals[2 * t];
    unsigned v1 = totals[2 * t + 1];
    unsigned run = v0 + v1;
    __shared__ unsigned s[TPB];
    s[t] = run;
    __syncthreads();
    for (int off = 1; off < TPB; off <<= 1) {
        unsigned x = (t >= off) ? s[t - off] : 0u;
        __syncthreads();
        s[t] += x;
        __syncthreads();
    }
    unsigned b0 = s[t] - run;
    base[2 * t]     = b0;
    base[2 * t + 1] = b0 + v0;
    if (t == TPB - 1) base[NB] = s[TPB - 1];
}

// S3: scatter edges into dst-bucket order.
// packed: {src:u32,  doff[0:10] | typ[12:15] | f16(norm)[16:31]}
__global__ __launch_bounds__(TPB) void scatter_kernel(const int* __restrict__ src,
                                                      const int* __restrict__ dst,
                                                      const int* __restrict__ typ,
                                                      const float* __restrict__ norm,
                                                      const unsigned* __restrict__ blockhist,
                                                      const unsigned* __restrict__ base,
                                                      uint2* __restrict__ packed,
                                                      int E, int per) {
    __shared__ unsigned cnt[NB];
    int blk = blockIdx.x;
    for (int i = threadIdx.x; i < NB; i += TPB)
        cnt[i] = blockhist[(size_t)blk * NB + i] + base[i];
    __syncthreads();
    int e0 = blk * per;
    int e1 = min(e0 + per, E);
    const int4*   src4 = (const int4*)src;
    const int4*   dst4 = (const int4*)dst;
    const int4*   typ4 = (const int4*)typ;
    const float4* nrm4 = (const float4*)norm;
    int g0 = e0 >> 2, g1 = e1 >> 2;

#define PUT(SS, DD, TT, NN)                                                       \
    {                                                                             \
        unsigned _d = (unsigned)(DD);                                             \
        unsigned _bucket = _d >> BSH;                                             \
        unsigned _pos = atomicAdd(&cnt[_bucket], 1u);                             \
        unsigned _w1 = (_d & ((1u << BSH) - 1u)) | (((unsigned)(TT)) << 12) |     \
                       ((unsigned)__half_as_ushort(__float2half_rn(NN)) << 16);   \
        packed[_pos] = make_uint2((unsigned)(SS), _w1);                           \
    }

    for (int g = g0 + threadIdx.x; g < g1; g += TPB) {
        int4 s = src4[g];
        int4 d = dst4[g];
        int4 t = typ4[g];
        float4 nm = nrm4[g];
        PUT(s.x, d.x, t.x, nm.x)
        PUT(s.y, d.y, t.y, nm.y)
        PUT(s.z, d.z, t.z, nm.z)
        PUT(s.w, d.w, t.w, nm.w)
    }
    for (int e = (g1 << 2) + threadIdx.x; e < e1; e += TPB)   // tail (E%4)
        PUT(src[e], dst[e], typ[e], norm[e])
#undef PUT
}

// Edge pass: one workgroup per 2048-node dst tile. LDS accumulation, fused
// epilogue (bias, relu, skip-add, optional store, optional w_mlp dot partial).
__global__ __launch_bounds__(TPB) void bucket_edge_kernel(
    const uint2* __restrict__ packed,
    const unsigned* __restrict__ base,
    const float2* __restrict__ x2,        // gather source [N]
    const float* __restrict__ Wl,         // [64] this layer
    const float* __restrict__ bias2,      // [2]
    const float2* __restrict__ skip2,     // nullable
    float2* __restrict__ out2,            // nullable
    const float2* __restrict__ w2,        // nullable (w_mlp as float2[N])
    float* __restrict__ acc,              // dot accumulator
    int N, int do_relu)
{
    __shared__ float acc0[1 << BSH];
    __shared__ float acc1[1 << BSH];
    __shared__ float sW[64];
    __shared__ float wred[4];

    int t = threadIdx.x;
#pragma unroll
    for (int k = 0; k < (1 << BSH) / TPB; ++k) {
        acc0[k * TPB + t] = 0.f;
        acc1[k * TPB + t] = 0.f;
    }
    if (t < 64) sW[t] = Wl[t];
    __syncthreads();

    int b  = blockIdx.x;
    int e0 = (int)base[b];
    int e1 = (int)base[b + 1];

    for (int e = e0 + t; e < e1; e += 2 * TPB) {
        uint2 p0 = packed[e];
        int e2 = e + TPB;
        bool has2 = e2 < e1;
        uint2 p1 = has2 ? packed[e2] : make_uint2(0u, 0u);

        float2 xv0 = x2[p0.x];
        float2 xv1 = has2 ? x2[p1.x] : make_float2(0.f, 0.f);

        {
            unsigned w1  = p0.y;
            unsigned dof = w1 & ((1u << BSH) - 1u);
            int wb = (int)((w1 >> 12) & 15u) << 2;
            float nm = __half2float(__ushort_as_half((unsigned short)(w1 >> 16)));
            float m0 = (xv0.x * sW[wb + 0] + xv0.y * sW[wb + 2]) * nm;
            float m1 = (xv0.x * sW[wb + 1] + xv0.y * sW[wb + 3]) * nm;
            atomicAdd(&acc0[dof], m0);
            atomicAdd(&acc1[dof], m1);
        }
        if (has2) {
            unsigned w1  = p1.y;
            unsigned dof = w1 & ((1u << BSH) - 1u);
            int wb = (int)((w1 >> 12) & 15u) << 2;
            float nm = __half2float(__ushort_as_half((unsigned short)(w1 >> 16)));
            float m0 = (xv1.x * sW[wb + 0] + xv1.y * sW[wb + 2]) * nm;
            float m1 = (xv1.x * sW[wb + 1] + xv1.y * sW[wb + 3]) * nm;
            atomicAdd(&acc0[dof], m0);
            atomicAdd(&acc1[dof], m1);
        }
    }
    __syncthreads();

    float b0 = bias2[0], b1 = bias2[1];
    int nodeBase = b << BSH;
    float part = 0.f;
#pragma unroll
    for (int k = 0; k < (1 << BSH) / TPB; ++k) {
        int i = k * TPB + t;
        int node = nodeBase + i;
        if (node < N) {
            float v0 = acc0[i] + b0;
            float v1 = acc1[i] + b1;
            if (do_relu) { v0 = fmaxf(v0, 0.f); v1 = fmaxf(v1, 0.f); }
            if (skip2) { float2 sv = skip2[node]; v0 += sv.x; v1 += sv.y; }
            if (out2)  out2[node] = make_float2(v0, v1);
            if (w2)    { float2 wv = w2[node]; part += v0 * wv.x + v1 * wv.y; }
        }
    }
    if (w2) {
        for (int off = 32; off > 0; off >>= 1) part += __shfl_down(part, off, 64);
        int lane = t & 63, wv = t >> 6;
        if (lane == 0) wred[wv] = part;
        __syncthreads();
        if (t == 0) atomicAdd(acc, wred[0] + wred[1] + wred[2] + wred[3]);
    }
}

// ============================ fallback path (round-1, known-good) ============================

__global__ void zero_kernel(float4* __restrict__ p, int n4) {
    int i = blockIdx.x * blockDim.x + threadIdx.x;
    int stride = gridDim.x * blockDim.x;
    for (; i < n4; i += stride) p[i] = make_float4(0.f, 0.f, 0.f, 0.f);
}

__global__ __launch_bounds__(256) void edge_kernel(
    const float* __restrict__ x, const int* __restrict__ src,
    const int* __restrict__ dst, const int* __restrict__ typ,
    const float* __restrict__ norm, const float* __restrict__ Wl,
    float* __restrict__ h, int E)
{
    __shared__ float sW[64];
    if (threadIdx.x < 64) sW[threadIdx.x] = Wl[threadIdx.x];
    __syncthreads();
    const float2* __restrict__ x2 = (const float2*)x;
    int tid = blockIdx.x * blockDim.x + threadIdx.x;
    int stride = gridDim.x * blockDim.x;
    for (int e = tid; e < E; e += stride) {
        int s = src[e], d = dst[e], t = typ[e];
        float nm = norm[e];
        float2 xv = x2[s];
        int wb = t << 2;
        float m0 = (xv.x * sW[wb + 0] + xv.y * sW[wb + 2]) * nm;
        float m1 = (xv.x * sW[wb + 1] + xv.y * sW[wb + 3]) * nm;
        atomicAdd(&h[2 * (size_t)d],     m0);
        atomicAdd(&h[2 * (size_t)d + 1], m1);
    }
}

__global__ void node_kernel(const float* __restrict__ h, const float* __restrict__ bias_l,
                            const float* __restrict__ skip, float* __restrict__ xout,
                            int N, int do_relu)
{
    float b0 = bias_l[0], b1 = bias_l[1];
    const float2* __restrict__ h2 = (const float2*)h;
    const float2* __restrict__ s2 = (const float2*)skip;
    float2* __restrict__ o2 = (float2*)xout;
    int i = blockIdx.x * blockDim.x + threadIdx.x;
    int stride = gridDim.x * blockDim.x;
    for (; i < N; i += stride) {
        float2 v = h2[i];
        v.x += b0; v.y += b1;
        if (do_relu) { v.x = fmaxf(v.x, 0.f); v.y = fmaxf(v.y, 0.f); }
        if (skip) { float2 sv = s2[i]; v.x += sv.x; v.y += sv.y; }
        o2[i] = v;
    }
}

__global__ __launch_bounds__(256) void dot_kernel(const float* __restrict__ a,
                                                  const float* __restrict__ b,
                                                  float* __restrict__ acc, int n)
{
    int i = blockIdx.x * blockDim.x + threadIdx.x;
    int stride = gridDim.x * blockDim.x;
    float s = 0.f;
    int n4 = n >> 2;
    const float4* __restrict__ a4 = (const float4*)a;
    const float4* __restrict__ b4 = (const float4*)b;
    for (int g = i; g < n4; g += stride) {
        float4 av = a4[g], bv = b4[g];
        s += av.x * bv.x + av.y * bv.y + av.z * bv.z + av.w * bv.w;
    }
    for (int e = (n4 << 2) + i; e < n; e += stride) s += a[e] * b[e];
    for (int off = 32; off > 0; off >>= 1) s += __shfl_down(s, off, 64);
    __shared__ float wsum[4];
    int lane = threadIdx.x & 63, wv = threadIdx.x >> 6;
    if (lane == 0) wsum[wv] = s;
    __syncthreads();
    if (threadIdx.x == 0) atomicAdd(acc, wsum[0] + wsum[1] + wsum[2] + wsum[3]);
}

// ============================ launch ============================

static inline size_t align256(size_t x) { return (x + 255) & ~(size_t)255; }

extern "C" void kernel_launch(void* const* d_in, const int* in_sizes, int n_in,
                              void* d_out, int out_size, void* d_ws, size_t ws_size,
                              hipStream_t stream) {
    const float* features = (const float*)d_in[0];   // [N*2]
    const float* norm     = (const float*)d_in[1];   // [E]
    const float* V        = (const float*)d_in[2];   // [L,B,2,2]
    const float* comp     = (const float*)d_in[3];   // [L,R,B]
    const float* bias     = (const float*)d_in[4];   // [L,2]
    const float* w_mlp    = (const float*)d_in[5];   // [N*2]
    const float* b_mlp    = (const float*)d_in[6];   // [1]
    const int*   esrc     = (const int*)d_in[7];
    const int*   edst     = (const int*)d_in[8];
    const int*   etyp     = (const int*)d_in[9];

    int NH = in_sizes[0];
    int N  = NH / 2;
    int E  = in_sizes[7];

    char* ws = (char*)d_ws;
    size_t oA    = 0;
    size_t oB    = align256(oA + (size_t)NH * 4);
    size_t oC    = align256(oB + (size_t)NH * 4);
    size_t oW    = align256(oC + (size_t)NH * 4);
    size_t oAcc  = align256(oW + 1024);
    size_t oBase = align256(oAcc + 4);
    size_t oTot  = align256(oBase + (size_t)(NB + 1) * 4);
    size_t oHist = align256(oTot + (size_t)NB * 4);
    size_t oPack = align256(oHist + (size_t)SBLK * NB * 4);
    size_t REQ   = oPack + (size_t)E * 8;

    float* A   = (float*)(ws + oA);
    float* B   = (float*)(ws + oB);
    float* C   = (float*)(ws + oC);
    float* W   = (float*)(ws + oW);
    float* acc = (float*)(ws + oAcc);

    prep_kernel<<<1, 256, 0, stream>>>(V, comp, W, acc);

    if (ws_size >= REQ && N <= (1 << 20)) {
        unsigned* base      = (unsigned*)(ws + oBase);
        unsigned* totals    = (unsigned*)(ws + oTot);
        unsigned* blockhist = (unsigned*)(ws + oHist);
        uint2*    packed    = (uint2*)(ws + oPack);

        int per = (((E + SBLK - 1) / SBLK) + 3) & ~3;   // multiple of 4

        hist_kernel   <<<SBLK, TPB, 0, stream>>>(edst, blockhist, E, per);
        colscan_kernel<<<NB,   TPB, 0, stream>>>(blockhist, totals);
        scan_kernel   <<<1,    TPB, 0, stream>>>(totals, base);
        scatter_kernel<<<SBLK, TPB, 0, stream>>>(esrc, edst, etyp, norm,
                                                 blockhist, base, packed, E, per);

        int nbkt = (N + (1 << BSH) - 1) >> BSH;
        const float2* feat2 = (const float2*)features;
        const float2* w2    = (const float2*)w_mlp;

        // L0: A = relu(h0 + b0)
        bucket_edge_kernel<<<nbkt, TPB, 0, stream>>>(packed, base, feat2, W + 0,
            bias + 0, nullptr, (float2*)A, nullptr, acc, N, 1);
        // L1: B = relu(h1 + b1) + features
        bucket_edge_kernel<<<nbkt, TPB, 0, stream>>>(packed, base, (const float2*)A, W + 64,
            bias + 2, feat2, (float2*)B, nullptr, acc, N, 1);
        // L2: C = relu(h2 + b2)
        bucket_edge_kernel<<<nbkt, TPB, 0, stream>>>(packed, base, (const float2*)B, W + 128,
            bias + 4, nullptr, (float2*)C, nullptr, acc, N, 1);
        // L3: x4 = (h3 + b3) + B, fused dot with w_mlp (x4 not stored)
        bucket_edge_kernel<<<nbkt, TPB, 0, stream>>>(packed, base, (const float2*)C, W + 192,
            bias + 6, (const float2*)B, nullptr, w2, acc, N, 0);
    } else {
        // fallback: round-1 atomic path
        int zb = (NH / 4 + 255) / 256;
        int eb = (E / 4 + 255) / 256;
        int nb = (N + 255) / 256;
        int db = (NH / 4 + 255) / 256;

        zero_kernel<<<zb, 256, 0, stream>>>((float4*)A, NH / 4);
        edge_kernel<<<eb, 256, 0, stream>>>(features, esrc, edst, etyp, norm, W + 0, A, E);
        node_kernel<<<nb, 256, 0, stream>>>(A, bias + 0, nullptr, A, N, 1);

        zero_kernel<<<zb, 256, 0, stream>>>((float4*)B, NH / 4);
        edge_kernel<<<eb, 256, 0, stream>>>(A, esrc, edst, etyp, norm, W + 64, B, E);
        node_kernel<<<nb, 256, 0, stream>>>(B, bias + 2, features, B, N, 1);

        zero_kernel<<<zb, 256, 0, stream>>>((float4*)C, NH / 4);
        edge_kernel<<<eb, 256, 0, stream>>>(B, esrc, edst, etyp, norm, W + 128, C, E);
        node_kernel<<<nb, 256, 0, stream>>>(C, bias + 4, nullptr, C, N, 1);

        zero_kernel<<<zb, 256, 0, stream>>>((float4*)A, NH / 4);
        edge_kernel<<<eb, 256, 0, stream>>>(C, esrc, edst, etyp, norm, W + 192, A, E);
        node_kernel<<<nb, 256, 0, stream>>>(A, bias + 6, B, A, N, 0);

        dot_kernel<<<db, 256, 0, stream>>>(A, w_mlp, acc, NH);
    }

    finalize_kernel<<<1, 1, 0, stream>>>(acc, b_mlp, (float*)d_out);
}